// Round 1
// baseline (615.614 us; speedup 1.0000x reference)
//
#include <hip/hip_runtime.h>
#include <math.h>

typedef __attribute__((ext_vector_type(8))) __bf16 bf16x8;
typedef __attribute__((ext_vector_type(4))) float f32x4;

#define NBATCH 8
#define SEQ    1024
#define NHEAD  16
#define DHEAD  64
#define HID    1024
#define MLPD   4096

static __device__ __forceinline__ unsigned short f2bf(float f) {
  unsigned int u = __float_as_uint(f);
  u += 0x7fffu + ((u >> 16) & 1u);
  return (unsigned short)(u >> 16);
}

// ---------- transpose: in f32 (R x C) -> out bf16 (C x R) ----------
__global__ __launch_bounds__(256) void k_transpose(const float* __restrict__ in,
                                                   unsigned short* __restrict__ out,
                                                   int R, int C) {
  __shared__ float t[32][33];
  const int tx = threadIdx.x & 31, ty = threadIdx.x >> 5;  // 32 x 8
  const int c0 = blockIdx.x * 32, r0 = blockIdx.y * 32;
#pragma unroll
  for (int j = 0; j < 4; ++j)
    t[ty + j * 8][tx] = in[(size_t)(r0 + ty + j * 8) * C + c0 + tx];
  __syncthreads();
#pragma unroll
  for (int j = 0; j < 4; ++j)
    out[(size_t)(c0 + ty + j * 8) * R + r0 + tx] = f2bf(t[tx][ty + j * 8]);
}

// ---------- pack q/k/v biases into one 3072 vector ----------
__global__ void k_pack_bias(const float* __restrict__ bq, const float* __restrict__ bk,
                            const float* __restrict__ bv, float* __restrict__ o) {
  int i = blockIdx.x * 256 + threadIdx.x;
  if (i < 3 * HID) {
    float v = (i < HID) ? bq[i] : (i < 2 * HID ? bk[i - HID] : bv[i - 2 * HID]);
    o[i] = v;
  }
}

// ---------- layernorm: f32 row (1024) -> bf16 row ----------
__global__ __launch_bounds__(256) void k_ln(const float* __restrict__ x,
                                            const float* __restrict__ gw,
                                            const float* __restrict__ bw,
                                            unsigned short* __restrict__ y) {
  __shared__ float red[2][4];
  const int row = blockIdx.x;
  const int tid = threadIdx.x;
  const float4 v = ((const float4*)(x + (size_t)row * HID))[tid];
  float sum = v.x + v.y + v.z + v.w;
  float sq  = v.x * v.x + v.y * v.y + v.z * v.z + v.w * v.w;
#pragma unroll
  for (int off = 32; off >= 1; off >>= 1) {
    sum += __shfl_xor(sum, off);
    sq  += __shfl_xor(sq, off);
  }
  if ((tid & 63) == 0) { red[0][tid >> 6] = sum; red[1][tid >> 6] = sq; }
  __syncthreads();
  sum = red[0][0] + red[0][1] + red[0][2] + red[0][3];
  sq  = red[1][0] + red[1][1] + red[1][2] + red[1][3];
  const float mu  = sum * (1.0f / HID);
  const float var = sq * (1.0f / HID) - mu * mu;
  const float rs  = rsqrtf(var + 1e-5f);
  const float4 g4 = ((const float4*)gw)[tid];
  const float4 b4 = ((const float4*)bw)[tid];
  ushort4 ov;
  ov.x = f2bf((v.x - mu) * rs * g4.x + b4.x);
  ov.y = f2bf((v.y - mu) * rs * g4.y + b4.y);
  ov.z = f2bf((v.z - mu) * rs * g4.z + b4.z);
  ov.w = f2bf((v.w - mu) * rs * g4.w + b4.w);
  ((ushort4*)(y + (size_t)row * HID))[tid] = ov;
}

// ---------- NT GEMM: C(MxN) = A(MxK) * BT(NxK)^T, bf16 in, f32 acc ----------
// EPI 0: bf16 store, +bias. EPI 1: +bias, gelu(tanh), bf16 store.
// EPI 2: +bias, +res (f32), f32 store.
template <int EPI>
__global__ __launch_bounds__(256) void k_gemm(const unsigned short* __restrict__ A,
                                              const unsigned short* __restrict__ BT,
                                              const float* __restrict__ bias,
                                              const float* __restrict__ res,
                                              void* __restrict__ Cout,
                                              int M, int N, int K) {
  __shared__ unsigned short As[128 * 40];
  __shared__ unsigned short Bs[128 * 40];
  const int tid  = threadIdx.x;
  const int lane = tid & 63;
  const int w    = tid >> 6;
  const int wr   = w >> 1, wc = w & 1;
  const int l15  = lane & 15, g = lane >> 4;
  const int m0 = blockIdx.y * 128, n0 = blockIdx.x * 128;

  f32x4 acc[4][4] = {};

  const int srow = tid >> 2;        // 0..63
  const int scol = (tid & 3) * 8;   // 0,8,16,24

  for (int k0 = 0; k0 < K; k0 += 32) {
    __syncthreads();
#pragma unroll
    for (int c = 0; c < 2; ++c) {
      int row = srow + c * 64;
      *(uint4*)(&As[row * 40 + scol]) =
          *(const uint4*)(&A[(size_t)(m0 + row) * K + k0 + scol]);
      *(uint4*)(&Bs[row * 40 + scol]) =
          *(const uint4*)(&BT[(size_t)(n0 + row) * K + k0 + scol]);
    }
    __syncthreads();
    bf16x8 af[4], bfr[4];
#pragma unroll
    for (int m = 0; m < 4; ++m)
      af[m] = *(const bf16x8*)(&As[(wr * 64 + m * 16 + l15) * 40 + g * 8]);
#pragma unroll
    for (int n = 0; n < 4; ++n)
      bfr[n] = *(const bf16x8*)(&Bs[(wc * 64 + n * 16 + l15) * 40 + g * 8]);
#pragma unroll
    for (int m = 0; m < 4; ++m)
#pragma unroll
      for (int n = 0; n < 4; ++n)
        acc[m][n] = __builtin_amdgcn_mfma_f32_16x16x32_bf16(af[m], bfr[n], acc[m][n], 0, 0, 0);
  }

#pragma unroll
  for (int m = 0; m < 4; ++m) {
#pragma unroll
    for (int n = 0; n < 4; ++n) {
      const int col = n0 + wc * 64 + n * 16 + l15;
      const float bc = bias[col];
#pragma unroll
      for (int r = 0; r < 4; ++r) {
        const int row = m0 + wr * 64 + m * 16 + g * 4 + r;
        const size_t idx = (size_t)row * N + col;
        float v = acc[m][n][r] + bc;
        if constexpr (EPI == 0) {
          ((unsigned short*)Cout)[idx] = f2bf(v);
        } else if constexpr (EPI == 1) {
          float tv = tanhf(0.7978845608028654f * (v + 0.044715f * v * v * v));
          ((unsigned short*)Cout)[idx] = f2bf(0.5f * v * (1.0f + tv));
        } else {
          ((float*)Cout)[idx] = v + res[idx];
        }
      }
    }
  }
}

// ---------- flash attention: qkv (M x 3072) bf16 -> attn out (M x 1024) bf16 ----------
__global__ __launch_bounds__(256) void k_attn(const unsigned short* __restrict__ qkv,
                                              unsigned short* __restrict__ outp) {
  __shared__ unsigned short P_lds[4][16 * 40];
  const int tid  = threadIdx.x;
  const int lane = tid & 63;
  const int w    = tid >> 6;
  const int l15  = lane & 15, g = lane >> 4;
  const int nh = blockIdx.y;
  const int nb = nh >> 4, h = nh & 15;
  const int qbase = blockIdx.x * 64 + w * 16;
  const size_t RS = 3 * HID;

  const unsigned short* Qp = qkv + (size_t)(nb * SEQ + qbase) * RS + h * DHEAD;
  const unsigned short* Kp = qkv + (size_t)(nb * SEQ) * RS + HID + h * DHEAD;
  const unsigned short* Vp = qkv + (size_t)(nb * SEQ) * RS + 2 * HID + h * DHEAD;

  bf16x8 aq[2];
#pragma unroll
  for (int t = 0; t < 2; ++t)
    aq[t] = *(const bf16x8*)(&Qp[(size_t)l15 * RS + t * 32 + g * 8]);

  f32x4 o[4] = {};
  float mrow[4], srow[4];
#pragma unroll
  for (int r = 0; r < 4; ++r) { mrow[r] = -INFINITY; srow[r] = 0.0f; }

  for (int kb = 0; kb < SEQ; kb += 32) {
    f32x4 S[2];
#pragma unroll
    for (int c = 0; c < 2; ++c) {
      f32x4 sa = {};
#pragma unroll
      for (int t = 0; t < 2; ++t) {
        bf16x8 bk = *(const bf16x8*)(&Kp[(size_t)(kb + c * 16 + l15) * RS + t * 32 + g * 8]);
        sa = __builtin_amdgcn_mfma_f32_16x16x32_bf16(aq[t], bk, sa, 0, 0, 0);
      }
      S[c] = sa;
    }
#pragma unroll
    for (int r = 0; r < 4; ++r) {
      float s0 = S[0][r] * 0.125f, s1 = S[1][r] * 0.125f;
      float tmax = fmaxf(s0, s1);
#pragma unroll
      for (int off = 8; off >= 1; off >>= 1)
        tmax = fmaxf(tmax, __shfl_xor(tmax, off));
      float mnew = fmaxf(mrow[r], tmax);
      float sc = __expf(mrow[r] - mnew);
      mrow[r] = mnew;
      float p0 = __expf(s0 - mnew), p1 = __expf(s1 - mnew);
      P_lds[w][(g * 4 + r) * 40 + l15]      = f2bf(p0);
      P_lds[w][(g * 4 + r) * 40 + 16 + l15] = f2bf(p1);
      float ts = p0 + p1;
#pragma unroll
      for (int off = 8; off >= 1; off >>= 1)
        ts += __shfl_xor(ts, off);
      srow[r] = srow[r] * sc + ts;
#pragma unroll
      for (int dt = 0; dt < 4; ++dt) o[dt][r] *= sc;
    }
    bf16x8 pa = *(const bf16x8*)(&P_lds[w][l15 * 40 + g * 8]);
#pragma unroll
    for (int dt = 0; dt < 4; ++dt) {
      union { unsigned short s[8]; bf16x8 v; } bv;
#pragma unroll
      for (int j = 0; j < 8; ++j)
        bv.s[j] = Vp[(size_t)(kb + g * 8 + j) * RS + dt * 16 + l15];
      o[dt] = __builtin_amdgcn_mfma_f32_16x16x32_bf16(pa, bv.v, o[dt], 0, 0, 0);
    }
  }
#pragma unroll
  for (int dt = 0; dt < 4; ++dt)
#pragma unroll
    for (int r = 0; r < 4; ++r)
      outp[(size_t)(nb * SEQ + qbase + g * 4 + r) * HID + h * DHEAD + dt * 16 + l15] =
          f2bf(o[dt][r] / srow[r]);
}

extern "C" void kernel_launch(void* const* d_in, const int* in_sizes, int n_in,
                              void* d_out, int out_size, void* d_ws, size_t ws_size,
                              hipStream_t stream) {
  const float* x    = (const float*)d_in[0];
  const float* ln0g = (const float*)d_in[1];
  const float* ln0b = (const float*)d_in[2];
  const float* wq   = (const float*)d_in[3];
  const float* bq   = (const float*)d_in[4];
  const float* wk   = (const float*)d_in[5];
  const float* bk   = (const float*)d_in[6];
  const float* wv   = (const float*)d_in[7];
  const float* bv   = (const float*)d_in[8];
  const float* wo   = (const float*)d_in[9];
  const float* bo   = (const float*)d_in[10];
  const float* ln1g = (const float*)d_in[11];
  const float* ln1b = (const float*)d_in[12];
  const float* w1   = (const float*)d_in[13];
  const float* b1   = (const float*)d_in[14];
  const float* w2   = (const float*)d_in[15];
  const float* b2   = (const float*)d_in[16];
  float* out = (float*)d_out;

  char* ws = (char*)d_ws;
  // workspace layout (bytes)
  unsigned short* qkvT = (unsigned short*)(ws + 0);          // 3072x1024 bf16   (6 MB)
  unsigned short* woT  = (unsigned short*)(ws + 6291456);    // 1024x1024 bf16   (2 MB)
  unsigned short* w1T  = (unsigned short*)(ws + 8388608);    // 4096x1024 bf16   (8 MB)
  unsigned short* w2T  = (unsigned short*)(ws + 16777216);   // 1024x4096 bf16   (8 MB)
  float*          bqkv = (float*)(ws + 25165824);            // 3072 f32
  unsigned short* ybuf = (unsigned short*)(ws + 25178112);   // 8192x1024 bf16   (16 MB)
  unsigned short* qkv  = (unsigned short*)(ws + 41955328);   // 8192x3072 bf16   (48 MB)
  unsigned short* att  = (unsigned short*)(ws + 92286976);   // 8192x1024 bf16   (16 MB)
  unsigned short* hbuf = qkv;  // 8192x4096 bf16 (64 MB) overlays qkv+att (both dead)

  const int M = NBATCH * SEQ;  // 8192

  // weight prep
  k_transpose<<<dim3(32, 32),  256, 0, stream>>>(wq, qkvT,                        HID,  HID);
  k_transpose<<<dim3(32, 32),  256, 0, stream>>>(wk, qkvT + (size_t)1024 * HID,   HID,  HID);
  k_transpose<<<dim3(32, 32),  256, 0, stream>>>(wv, qkvT + (size_t)2048 * HID,   HID,  HID);
  k_transpose<<<dim3(32, 32),  256, 0, stream>>>(wo, woT,                         HID,  HID);
  k_transpose<<<dim3(128, 32), 256, 0, stream>>>(w1, w1T,                         HID,  MLPD);
  k_transpose<<<dim3(32, 128), 256, 0, stream>>>(w2, w2T,                         MLPD, HID);
  k_pack_bias<<<dim3(12), 256, 0, stream>>>(bq, bk, bv, bqkv);

  // LN0 -> y
  k_ln<<<dim3(M), 256, 0, stream>>>(x, ln0g, ln0b, ybuf);
  // QKV: qkv = y @ [wq|wk|wv] + b   (M x 3072)
  k_gemm<0><<<dim3(24, 64), 256, 0, stream>>>(ybuf, qkvT, bqkv, nullptr, (void*)qkv, M, 3 * HID, HID);
  // attention
  k_attn<<<dim3(16, 128), 256, 0, stream>>>(qkv, att);
  // x1 = x + att @ wo + bo  -> d_out (f32)
  k_gemm<2><<<dim3(8, 64), 256, 0, stream>>>(att, woT, bo, x, (void*)out, M, HID, HID);
  // LN1 -> y
  k_ln<<<dim3(M), 256, 0, stream>>>(out, ln1g, ln1b, ybuf);
  // h = gelu(y @ w1 + b1)  (M x 4096)
  k_gemm<1><<<dim3(32, 64), 256, 0, stream>>>(ybuf, w1T, b1, nullptr, (void*)hbuf, M, MLPD, HID);
  // out = d_out + h @ w2 + b2
  k_gemm<2><<<dim3(8, 64), 256, 0, stream>>>(hbuf, w2T, b2, out, (void*)out, M, HID, MLPD);
}